// Round 5
// baseline (1023.188 us; speedup 1.0000x reference)
//
#include <hip/hip_runtime.h>

namespace {

constexpr int NROWS = 256, LSTEPS = 512, IN = 64, LAT = 32, HID = 128;

typedef _Float16 h2 __attribute__((ext_vector_type(2)));
typedef _Float16 h8 __attribute__((ext_vector_type(8)));

__device__ __forceinline__ float fast_sigmoid(float x) {
    return __fdividef(1.f, 1.f + __expf(-x));
}
__device__ __forceinline__ float fast_softplus(float x) {
    return fmaxf(x, 0.f) + log1pf(__expf(-fabsf(x)));
}
__device__ __forceinline__ float fast_tanh(float x) {
    float e = __expf(-2.f * fabsf(x));
    float t = __fdividef(1.f - e, 1.f + e);
    return copysignf(t, x);
}

__device__ __forceinline__ float dot2f(h2 w, h2 a, float c) {
#if __has_builtin(__builtin_amdgcn_fdot2)
    return __builtin_amdgcn_fdot2(w, a, c, false);
#else
    return fmaf((float)w[0], (float)a[0], fmaf((float)w[1], (float)a[1], c));
#endif
}

__device__ __forceinline__ h2 packw(float a, float b) {
    h2 r; r[0] = (_Float16)a; r[1] = (_Float16)b; return r;
}

// NPAIR f16x2 register weights vs 2*NPAIR f16 LDS activations (16B blocks),
// 4 split accumulators, optional carried-in accumulator.
template<int BASE, int NPAIR>
__device__ __forceinline__ float dotp2(const _Float16* act, const h2 (&w)[120], float init) {
    float a0 = init, a1 = 0.f, a2 = 0.f, a3 = 0.f;
#pragma unroll
    for (int i = 0; i < NPAIR / 4; ++i) {
        h8 b = *(const h8*)(act + 8 * i);
        a0 = dot2f(w[BASE + 4 * i + 0], __builtin_shufflevector(b, b, 0, 1), a0);
        a1 = dot2f(w[BASE + 4 * i + 1], __builtin_shufflevector(b, b, 2, 3), a1);
        a2 = dot2f(w[BASE + 4 * i + 2], __builtin_shufflevector(b, b, 4, 5), a2);
        a3 = dot2f(w[BASE + 4 * i + 3], __builtin_shufflevector(b, b, 6, 7), a3);
    }
    return (a0 + a1) + (a2 + a3);
}

} // namespace

// One block per batch row. 4-barrier schedule:
//  A: qzcx (Y team, in-wave reduce -> z) || pxcz_h partial in reg (X) || gh (all)
//  B: pxcz_z + in-wave reduce -> x_gen (X) || gi_z partials (Y)
//  D: gi_x partials (all) + x refresh
//  G: GRU gates (t<128), h update
__global__ __launch_bounds__(512)
__attribute__((amdgpu_waves_per_eu(2, 2)))
void vrnn_kernel(
    const float* __restrict__ X, const float* __restrict__ EZ, const float* __restrict__ EX,
    const float* __restrict__ Wq, const float* __restrict__ bq,
    const float* __restrict__ Wp, const float* __restrict__ bp,
    const float* __restrict__ Wih, const float* __restrict__ Whh,
    const float* __restrict__ bih, const float* __restrict__ bhh,
    float* __restrict__ out)
{
    __shared__ alignas(16) _Float16 XH[192];        // [ x(64) | h(128) ]
    __shared__ alignas(16) _Float16 ZH[32];         // z_gen (f16)
    __shared__ alignas(16) _Float16 XZ[64];         // x_gen (f16)
    __shared__ alignas(16) float gh_part[384][4];   // 4 K-quarter partials
    __shared__ alignas(16) float gi_part[384][8];   // 0-1: z halves, 2-5: x quarters

    const int t = threadIdx.x;
    const int n = blockIdx.x;

    h2 wpk[120];

    // ---------------- per-thread static role indices ----------------
    // X team (t<256): pxcz pair j_p = t>>2, sub_p = t&3 (0/1 mean-kh, 2/3 raw-kh)
    // Y team: qzcx pair j_q = y>>3, sub_q = y&7 (0-3 mean k-slices, 4-7 raw)
    const int y = t - 256;

    // gh slices: X: s = 3t+i in [0,768); Y: s = 768+3y+i.  m = s>>2, kq = s&3
    int mg[3], kqg[3];
    // gi_x slices: same s pattern. m = s>>2, kq = s&3
    int mx[3], kqx[3];
    // gi_z slices (Y only): s = 3y+i in [0,768). m = s>>1, kh = s&1
    int mz[3], khz[3];
#pragma unroll
    for (int i = 0; i < 3; ++i) {
        int s = (t < 256) ? (3 * t + i) : (768 + 3 * y + i);
        mg[i] = s >> 2; kqg[i] = s & 3;
        mx[i] = s >> 2; kqx[i] = s & 3;
        if (t >= 256) { int sz = 3 * y + i; mz[i] = sz >> 1; khz[i] = sz & 1; }
        else { mz[i] = 0; khz[i] = 0; }
    }

    // ---------------- one-time weight load into registers ----------------
    if (t < 256) {
        const int j = t >> 2, sub = t & 3;
        const int o = (sub < 2) ? j : j + 64;   // pxcz out col (mean j / raw j)
        const int kh = sub & 1;
        // pxcz_h: K rows 32+64*kh .. +64  -> wpk[0..32)
#pragma unroll
        for (int p = 0; p < 32; ++p) { int k = 32 + 64 * kh + 2 * p;
            wpk[p] = packw(Wp[k * 128 + o], Wp[(k + 1) * 128 + o]); }
        // pxcz_z: K rows 16*kh .. +16 -> wpk[32..40)
#pragma unroll
        for (int p = 0; p < 8; ++p) { int k = 16 * kh + 2 * p;
            wpk[32 + p] = packw(Wp[k * 128 + o], Wp[(k + 1) * 128 + o]); }
        // gh quarters -> wpk[40..88)
#pragma unroll
        for (int i = 0; i < 3; ++i)
#pragma unroll
            for (int p = 0; p < 16; ++p) { int k = 32 * kqg[i] + 2 * p;
                wpk[40 + 16 * i + p] = packw(Whh[k * 384 + mg[i]], Whh[(k + 1) * 384 + mg[i]]); }
        // gi_x quarters -> wpk[88..112)
#pragma unroll
        for (int i = 0; i < 3; ++i)
#pragma unroll
            for (int p = 0; p < 8; ++p) { int k = 16 * kqx[i] + 2 * p;
                wpk[88 + 8 * i + p] = packw(Wih[k * 384 + mx[i]], Wih[(k + 1) * 384 + mx[i]]); }
    } else {
        const int j = y >> 3, sub = y & 7;
        const int o = (sub < 4) ? j : j + 32;   // qzcx out col
        const int k0 = (sub & 3) * 48;
        // qzcx: 24 pairs -> wpk[0..24)
#pragma unroll
        for (int p = 0; p < 24; ++p) { int k = k0 + 2 * p;
            wpk[p] = packw(Wq[k * 64 + o], Wq[(k + 1) * 64 + o]); }
        // gh quarters -> wpk[24..72)
#pragma unroll
        for (int i = 0; i < 3; ++i)
#pragma unroll
            for (int p = 0; p < 16; ++p) { int k = 32 * kqg[i] + 2 * p;
                wpk[24 + 16 * i + p] = packw(Whh[k * 384 + mg[i]], Whh[(k + 1) * 384 + mg[i]]); }
        // gi_z halves -> wpk[72..96)
#pragma unroll
        for (int i = 0; i < 3; ++i)
#pragma unroll
            for (int p = 0; p < 8; ++p) { int k = 64 + 16 * khz[i] + 2 * p;
                wpk[72 + 8 * i + p] = packw(Wih[k * 384 + mz[i]], Wih[(k + 1) * 384 + mz[i]]); }
        // gi_x quarters -> wpk[96..120)
#pragma unroll
        for (int i = 0; i < 3; ++i)
#pragma unroll
            for (int p = 0; p < 8; ++p) { int k = 16 * kqx[i] + 2 * p;
                wpk[96 + 8 * i + p] = packw(Wih[k * 384 + mx[i]], Wih[(k + 1) * 384 + mx[i]]); }
    }

    // ---------------- per-role biases & noise prefetch ----------------
    float bqm = 0.f, bqr = 0.f, bpm = 0.f, bpr = 0.f;
    float bir = 0.f, biz = 0.f, bin_ = 0.f, bhr = 0.f, bhz = 0.f, bhn = 0.f;
    if (t >= 256 && (y & 7) == 0) { bqm = bq[y >> 3]; bqr = bq[(y >> 3) + 32]; }
    if (t < 256 && (t & 3) == 0)  { bpm = bp[t >> 2]; bpr = bp[(t >> 2) + 64]; }
    if (t < 128) { bir = bih[t]; biz = bih[128 + t]; bin_ = bih[256 + t];
                   bhr = bhh[t]; bhz = bhh[128 + t]; bhn = bhh[256 + t]; }

    const float* Xrow = X + n * (LSTEPS * IN);
    float* orow = out + n * (LSTEPS * HID);
    float hreg = 0.f;
    if (t < 128) XH[64 + t] = (_Float16)0.f;
    if (t < 64)  XH[t] = (_Float16)Xrow[t];

    float ez_nxt = 0.f, ex_nxt = 0.f, xn_nxt = 0.f;
    if (t >= 256 && (y & 7) == 0) ez_nxt = EZ[n * LAT + (y >> 3)];
    if (t < 256 && (t & 3) == 0)  ex_nxt = EX[n * IN + (t >> 2)];
    __syncthreads();

    float ph = 0.f;   // pxcz h-part partial, carried A -> B

    for (int l = 0; l < LSTEPS; ++l) {
        const float ez_cur = ez_nxt, ex_cur = ex_nxt;
        if (l + 1 < LSTEPS) {
            if (t >= 256 && (y & 7) == 0) ez_nxt = EZ[(l + 1) * (NROWS * LAT) + n * LAT + (y >> 3)];
            if (t < 256 && (t & 3) == 0)  ex_nxt = EX[(l + 1) * (NROWS * IN) + n * IN + (t >> 2)];
            if (t < 64) xn_nxt = Xrow[(l + 1) * IN + t];
        }

        // ---------------- Phase A ----------------
        if (t < 256) {
            const int kh = t & 1;
            ph = dotp2<0, 32>(XH + 64 + 64 * kh, wpk, 0.f);           // pxcz_h
            float g0 = dotp2<40, 16>(XH + 64 + 32 * kqg[0], wpk, 0.f);
            float g1 = dotp2<56, 16>(XH + 64 + 32 * kqg[1], wpk, 0.f);
            float g2 = dotp2<72, 16>(XH + 64 + 32 * kqg[2], wpk, 0.f);
            gh_part[mg[0]][kqg[0]] = g0;
            gh_part[mg[1]][kqg[1]] = g1;
            gh_part[mg[2]][kqg[2]] = g2;
        } else {
            const int sub = y & 7, k0 = (sub & 3) * 48;
            float q = dotp2<0, 24>(XH + k0, wpk, 0.f);                 // qzcx partial
            float g0 = dotp2<24, 16>(XH + 64 + 32 * kqg[0], wpk, 0.f);
            float g1 = dotp2<40, 16>(XH + 64 + 32 * kqg[1], wpk, 0.f);
            float g2 = dotp2<56, 16>(XH + 64 + 32 * kqg[2], wpk, 0.f);
            gh_part[mg[0]][kqg[0]] = g0;
            gh_part[mg[1]][kqg[1]] = g1;
            gh_part[mg[2]][kqg[2]] = g2;
            // in-wave reduce over 4 k-slices, then mean<->raw swap
            q += __shfl_xor(q, 1);
            q += __shfl_xor(q, 2);
            float other = __shfl_xor(q, 4);
            if (sub == 0) {
                float z = (q + bqm) + fast_softplus(other + bqr) * ez_cur;
                ZH[y >> 3] = (_Float16)z;
            }
        }
        __syncthreads();

        // ---------------- Phase B ----------------
        if (t < 256) {
            const int kh = t & 1, sub = t & 3;
            float tot = dotp2<32, 8>(ZH + 16 * kh, wpk, ph);           // + z-part
            tot += __shfl_xor(tot, 1);                                  // combine kh
            float other = __shfl_xor(tot, 2);                           // mean<->raw
            if (sub == 0) {
                float xg = (tot + bpm) + fast_softplus(other + bpr) * ex_cur;
                XZ[t >> 2] = (_Float16)xg;
            }
        } else {
            gi_part[mz[0]][khz[0]] = dotp2<72, 8>(ZH + 16 * khz[0], wpk, 0.f);
            gi_part[mz[1]][khz[1]] = dotp2<80, 8>(ZH + 16 * khz[1], wpk, 0.f);
            gi_part[mz[2]][khz[2]] = dotp2<88, 8>(ZH + 16 * khz[2], wpk, 0.f);
        }
        __syncthreads();

        // ---------------- Phase D ----------------
        if (t < 256) {
            gi_part[mx[0]][2 + kqx[0]] = dotp2<88, 8>(XZ + 16 * kqx[0], wpk, 0.f);
            gi_part[mx[1]][2 + kqx[1]] = dotp2<96, 8>(XZ + 16 * kqx[1], wpk, 0.f);
            gi_part[mx[2]][2 + kqx[2]] = dotp2<104, 8>(XZ + 16 * kqx[2], wpk, 0.f);
            if (t < 64 && l + 1 < LSTEPS) XH[t] = (_Float16)xn_nxt;   // next x
        } else {
            gi_part[mx[0]][2 + kqx[0]] = dotp2<96, 8>(XZ + 16 * kqx[0], wpk, 0.f);
            gi_part[mx[1]][2 + kqx[1]] = dotp2<104, 8>(XZ + 16 * kqx[1], wpk, 0.f);
            gi_part[mx[2]][2 + kqx[2]] = dotp2<112, 8>(XZ + 16 * kqx[2], wpk, 0.f);
        }
        __syncthreads();

        // ---------------- Phase G: gates ----------------
        if (t < 128) {
            float4 a; float2 b2;
            a = *(const float4*)&gi_part[t][0];        b2 = *(const float2*)&gi_part[t][4];
            float gir = (a.x + a.y) + (a.z + a.w) + (b2.x + b2.y) + bir;
            a = *(const float4*)&gi_part[128 + t][0];  b2 = *(const float2*)&gi_part[128 + t][4];
            float giz = (a.x + a.y) + (a.z + a.w) + (b2.x + b2.y) + biz;
            a = *(const float4*)&gi_part[256 + t][0];  b2 = *(const float2*)&gi_part[256 + t][4];
            float gin = (a.x + a.y) + (a.z + a.w) + (b2.x + b2.y) + bin_;
            a = *(const float4*)&gh_part[t][0];
            float ghr = (a.x + a.y) + (a.z + a.w) + bhr;
            a = *(const float4*)&gh_part[128 + t][0];
            float ghz = (a.x + a.y) + (a.z + a.w) + bhz;
            a = *(const float4*)&gh_part[256 + t][0];
            float ghn = (a.x + a.y) + (a.z + a.w) + bhn;
            float r  = fast_sigmoid(gir + ghr);
            float zg = fast_sigmoid(giz + ghz);
            float nn = fast_tanh(fmaf(r, ghn, gin));
            float hnew = fmaf(zg, hreg - nn, nn);
            hreg = hnew;
            XH[64 + t] = (_Float16)hnew;
            orow[l * HID + t] = hnew;
        }
        __syncthreads();
    }

    if (t < 128) out[NROWS * LSTEPS * HID + n * HID + t] = hreg;
}

extern "C" void kernel_launch(void* const* d_in, const int* in_sizes, int n_in,
                              void* d_out, int out_size, void* d_ws, size_t ws_size,
                              hipStream_t stream) {
    const float* X   = (const float*)d_in[0];
    const float* EZ  = (const float*)d_in[1];
    const float* EX  = (const float*)d_in[2];
    const float* Wq  = (const float*)d_in[3];
    const float* bq  = (const float*)d_in[4];
    const float* Wp  = (const float*)d_in[5];
    const float* bp  = (const float*)d_in[6];
    const float* Wih = (const float*)d_in[7];
    const float* Whh = (const float*)d_in[8];
    const float* bih = (const float*)d_in[9];
    const float* bhh = (const float*)d_in[10];
    float* out = (float*)d_out;

    vrnn_kernel<<<dim3(NROWS), dim3(512), 0, stream>>>(
        X, EZ, EX, Wq, bq, Wp, bp, Wih, Whh, bih, bhh, out);
}

// Round 6
// 1013.490 us; speedup vs baseline: 1.0096x; 1.0096x over previous
//
#include <hip/hip_runtime.h>

namespace {

constexpr int NROWS = 256, LSTEPS = 512, IN = 64, LAT = 32, HID = 128;

typedef _Float16 h2 __attribute__((ext_vector_type(2)));
typedef _Float16 h8 __attribute__((ext_vector_type(8)));

__device__ __forceinline__ float fast_sigmoid(float x) {
    return __fdividef(1.f, 1.f + __expf(-x));
}
__device__ __forceinline__ float fast_softplus(float x) {
    // max(x,0) + log(1+exp(-|x|)) via HW v_exp/v_log (no branchy libm log1pf)
    return fmaxf(x, 0.f) + __logf(1.f + __expf(-fabsf(x)));
}
__device__ __forceinline__ float fast_tanh(float x) {
    float e = __expf(-2.f * fabsf(x));
    return copysignf(__fdividef(1.f - e, 1.f + e), x);
}
__device__ __forceinline__ float dot2f(h2 w, h2 a, float c) {
#if __has_builtin(__builtin_amdgcn_fdot2)
    return __builtin_amdgcn_fdot2(w, a, c, false);
#else
    return fmaf((float)w[0], (float)a[0], fmaf((float)w[1], (float)a[1], c));
#endif
}
__device__ __forceinline__ h2 packw(float a, float b) {
    h2 r; r[0] = (_Float16)a; r[1] = (_Float16)b; return r;
}

// NPAIR f16x2 register weights vs 2*NPAIR f16 LDS activations, 4 split accs.
template<int BASE, int NPAIR>
__device__ __forceinline__ float dotp2(const _Float16* act, const h2 (&w)[60], float init) {
    float a0 = init, a1 = 0.f, a2 = 0.f, a3 = 0.f;
#pragma unroll
    for (int i = 0; i < NPAIR / 4; ++i) {
        h8 b = *(const h8*)(act + 8 * i);
        a0 = dot2f(w[BASE + 4 * i + 0], __builtin_shufflevector(b, b, 0, 1), a0);
        a1 = dot2f(w[BASE + 4 * i + 1], __builtin_shufflevector(b, b, 2, 3), a1);
        a2 = dot2f(w[BASE + 4 * i + 2], __builtin_shufflevector(b, b, 4, 5), a2);
        a3 = dot2f(w[BASE + 4 * i + 3], __builtin_shufflevector(b, b, 6, 7), a3);
    }
    return (a0 + a1) + (a2 + a3);
}

} // namespace

// 1024 threads = 16 waves = 4 waves/SIMD (2x the latency hiding of 512).
// One block per batch row. 4-barrier schedule:
//  A: pxcz_h (X) + qzcx->z (Y, shfl-reduce) + gh slots 0,1 (all)
//  B: pxcz_z -> x_gen (X, shfl-reduce) + gi_z (Y) + gh slot 2 (X)
//  D: gi_x (all) + next-x refresh
//  G: GRU gates (t<128)
// X team t<512: t = j*8 + mr*4 + kq   (j: x_gen idx, mr: mean/raw, kq: K-quarter)
// Y team y=t-512: y = j*16 + mr*8 + k3 (j: z idx,    mr: mean/raw, k3: K-eighth)
__global__ __launch_bounds__(1024) void vrnn_kernel(
    const float* __restrict__ X, const float* __restrict__ EZ, const float* __restrict__ EX,
    const float* __restrict__ Wq, const float* __restrict__ bq,
    const float* __restrict__ Wp, const float* __restrict__ bp,
    const float* __restrict__ Wih, const float* __restrict__ Whh,
    const float* __restrict__ bih, const float* __restrict__ bhh,
    float* __restrict__ out)
{
    __shared__ alignas(16) _Float16 XH[192];        // [ x(64) | h(128) ]
    __shared__ alignas(16) _Float16 ZH[32];         // z_gen
    __shared__ alignas(16) _Float16 XZ[64];         // x_gen
    __shared__ alignas(16) float gi_part[384][12];  // [0:4) x-quarters, [4:6) z-halves
    __shared__ alignas(16) float gh_part[384][12];  // [0:8) h-eighths

    const int t = threadIdx.x;
    const int n = blockIdx.x;
    const int y = t - 512;

    h2 wpk[60];

    // gh slices: X covers s in [0,1536): s=3t+i. Y covers [1536,3072): s=1536+3y+i.
    int mh[3], k8h[3];
#pragma unroll
    for (int i = 0; i < 3; ++i) {
        int s = (t < 512) ? (3 * t + i) : (1536 + 3 * y + i);
        mh[i] = s >> 3; k8h[i] = s & 7;
    }
    // gi_x slices (1536 slots: s=t | 512+y | 1024+t)
    int mxA = 0, kxA = 0, mxB = 0, kxB = 0;
    if (t < 512) { mxA = t >> 2; kxA = t & 3; int s = 1024 + t; mxB = s >> 2; kxB = s & 3; }
    else         { int s = 512 + y; mxA = s >> 2; kxA = s & 3; }
    // gi_z slices (Y: 768 slots: s=y | 512+y for y<256)
    int mzA = 0, kzA = 0, mzB = 0, kzB = 0;
    if (t >= 512) { mzA = y >> 1; kzA = y & 1; int s = 512 + y; mzB = s >> 1; kzB = s & 1; }

    // ---------------- one-time weight load into registers ----------------
    if (t < 512) {
        const int j = t >> 3, mr = (t >> 2) & 1, kq = t & 3;
        const int o = j + mr * 64;                 // pxcz col (mean j / raw j+64)
        // pxcz_h: K rows 32+kq*32 .. +32 -> wpk[0..16)
#pragma unroll
        for (int p = 0; p < 16; ++p) { int k = 32 + kq * 32 + 2 * p;
            wpk[p] = packw(Wp[k * 128 + o], Wp[(k + 1) * 128 + o]); }
        // pxcz_z: K rows kq*8 .. +8 -> wpk[16..20)
#pragma unroll
        for (int p = 0; p < 4; ++p) { int k = kq * 8 + 2 * p;
            wpk[16 + p] = packw(Wp[k * 128 + o], Wp[(k + 1) * 128 + o]); }
        // gh eighths -> wpk[20..44)
#pragma unroll
        for (int i = 0; i < 3; ++i)
#pragma unroll
            for (int p = 0; p < 8; ++p) { int k = 16 * k8h[i] + 2 * p;
                wpk[20 + 8 * i + p] = packw(Whh[k * 384 + mh[i]], Whh[(k + 1) * 384 + mh[i]]); }
        // gi_x quarters -> wpk[44..52), [52..60)
#pragma unroll
        for (int p = 0; p < 8; ++p) { int k = 16 * kxA + 2 * p;
            wpk[44 + p] = packw(Wih[k * 384 + mxA], Wih[(k + 1) * 384 + mxA]); }
#pragma unroll
        for (int p = 0; p < 8; ++p) { int k = 16 * kxB + 2 * p;
            wpk[52 + p] = packw(Wih[k * 384 + mxB], Wih[(k + 1) * 384 + mxB]); }
    } else {
        const int j = y >> 4, mr = (y >> 3) & 1, k3 = y & 7;
        const int o = j + mr * 32;                 // qzcx col
        // qzcx: K rows 24*k3 .. +24 -> wpk[0..12)
#pragma unroll
        for (int p = 0; p < 12; ++p) { int k = 24 * k3 + 2 * p;
            wpk[p] = packw(Wq[k * 64 + o], Wq[(k + 1) * 64 + o]); }
        // gh eighths -> wpk[12..36)
#pragma unroll
        for (int i = 0; i < 3; ++i)
#pragma unroll
            for (int p = 0; p < 8; ++p) { int k = 16 * k8h[i] + 2 * p;
                wpk[12 + 8 * i + p] = packw(Whh[k * 384 + mh[i]], Whh[(k + 1) * 384 + mh[i]]); }
        // gi_z halves -> wpk[36..44), [44..52) (second only y<256)
#pragma unroll
        for (int p = 0; p < 8; ++p) { int k = 64 + 16 * kzA + 2 * p;
            wpk[36 + p] = packw(Wih[k * 384 + mzA], Wih[(k + 1) * 384 + mzA]); }
        if (y < 256) {
#pragma unroll
            for (int p = 0; p < 8; ++p) { int k = 64 + 16 * kzB + 2 * p;
                wpk[44 + p] = packw(Wih[k * 384 + mzB], Wih[(k + 1) * 384 + mzB]); }
        }
        // gi_x quarter -> wpk[52..60)
#pragma unroll
        for (int p = 0; p < 8; ++p) { int k = 16 * kxA + 2 * p;
            wpk[52 + p] = packw(Wih[k * 384 + mxA], Wih[(k + 1) * 384 + mxA]); }
    }

    // ---------------- per-role biases ----------------
    float bqm = 0.f, bqr = 0.f, bpm = 0.f, bpr = 0.f;
    float bir = 0.f, biz = 0.f, bin_ = 0.f, bhr = 0.f, bhz = 0.f, bhn = 0.f;
    if (t >= 512 && (y & 15) == 0) { bqm = bq[y >> 4]; bqr = bq[(y >> 4) + 32]; }
    if (t < 512 && (t & 7) == 0)   { bpm = bp[t >> 3]; bpr = bp[(t >> 3) + 64]; }
    if (t < 128) { bir = bih[t]; biz = bih[128 + t]; bin_ = bih[256 + t];
                   bhr = bhh[t]; bhz = bhh[128 + t]; bhn = bhh[256 + t]; }

    const float* Xrow = X + n * (LSTEPS * IN);
    float* orow = out + n * (LSTEPS * HID);
    float hreg = 0.f;
    if (t < 128) XH[64 + t] = (_Float16)0.f;
    if (t < 64)  XH[t] = (_Float16)Xrow[t];

    float ez_nxt = 0.f, ex_nxt = 0.f, xn_nxt = 0.f;
    if (t >= 512 && (y & 15) == 0) ez_nxt = EZ[n * LAT + (y >> 4)];
    if (t < 512 && (t & 7) == 0)   ex_nxt = EX[n * IN + (t >> 3)];
    __syncthreads();

    float ph = 0.f;   // pxcz h-part partial, carried A -> B

    for (int l = 0; l < LSTEPS; ++l) {
        const float ez_cur = ez_nxt, ex_cur = ex_nxt;
        if (l + 1 < LSTEPS) {
            if (t >= 512 && (y & 15) == 0) ez_nxt = EZ[(l + 1) * (NROWS * LAT) + n * LAT + (y >> 4)];
            if (t < 512 && (t & 7) == 0)   ex_nxt = EX[(l + 1) * (NROWS * IN) + n * IN + (t >> 3)];
            if (t < 64) xn_nxt = Xrow[(l + 1) * IN + t];
        }

        // ---------------- Phase A ----------------
        if (t < 512) {
            const int kq = t & 3;
            ph = dotp2<0, 16>(XH + 64 + 32 * kq, wpk, 0.f);            // pxcz_h
            float g0 = dotp2<20, 8>(XH + 64 + 16 * k8h[0], wpk, 0.f);
            float g1 = dotp2<28, 8>(XH + 64 + 16 * k8h[1], wpk, 0.f);
            gh_part[mh[0]][k8h[0]] = g0;
            gh_part[mh[1]][k8h[1]] = g1;
        } else {
            const int k3 = y & 7;
            float q = dotp2<0, 12>(XH + 24 * k3, wpk, 0.f);            // qzcx partial
            q += __shfl_xor(q, 1);
            q += __shfl_xor(q, 2);
            q += __shfl_xor(q, 4);
            float other = __shfl_xor(q, 8);                            // mean<->raw
            float g0 = dotp2<12, 8>(XH + 64 + 16 * k8h[0], wpk, 0.f);
            float g1 = dotp2<20, 8>(XH + 64 + 16 * k8h[1], wpk, 0.f);
            gh_part[mh[0]][k8h[0]] = g0;
            gh_part[mh[1]][k8h[1]] = g1;
            if ((y & 15) == 0) {
                float z = (q + bqm) + fast_softplus(other + bqr) * ez_cur;
                ZH[y >> 4] = (_Float16)z;
            }
        }
        __syncthreads();

        // ---------------- Phase B ----------------
        if (t < 512) {
            const int kq = t & 3;
            float tot = dotp2<16, 4>(ZH + 8 * kq, wpk, ph);            // + z-part
            tot += __shfl_xor(tot, 1);
            tot += __shfl_xor(tot, 2);
            float other = __shfl_xor(tot, 4);                          // mean<->raw
            float g2 = dotp2<36, 8>(XH + 64 + 16 * k8h[2], wpk, 0.f);
            gh_part[mh[2]][k8h[2]] = g2;
            if ((t & 7) == 0) {
                float xg = (tot + bpm) + fast_softplus(other + bpr) * ex_cur;
                XZ[t >> 3] = (_Float16)xg;
            }
        } else {
            float z0 = dotp2<36, 8>(ZH + 16 * kzA, wpk, 0.f);
            gi_part[mzA][4 + kzA] = z0;
            if (y < 256) {
                float z1 = dotp2<44, 8>(ZH + 16 * kzB, wpk, 0.f);
                gi_part[mzB][4 + kzB] = z1;
            }
            float g2 = dotp2<28, 8>(XH + 64 + 16 * k8h[2], wpk, 0.f);
            gh_part[mh[2]][k8h[2]] = g2;
        }
        __syncthreads();

        // ---------------- Phase D ----------------
        if (t < 512) {
            float x0 = dotp2<44, 8>(XZ + 16 * kxA, wpk, 0.f);
            float x1 = dotp2<52, 8>(XZ + 16 * kxB, wpk, 0.f);
            gi_part[mxA][kxA] = x0;
            gi_part[mxB][kxB] = x1;
            if (t < 64 && l + 1 < LSTEPS) XH[t] = (_Float16)xn_nxt;    // next x
        } else {
            float x2 = dotp2<52, 8>(XZ + 16 * kxA, wpk, 0.f);
            gi_part[mxA][kxA] = x2;
        }
        __syncthreads();

        // ---------------- Phase G: gates ----------------
        if (t < 128) {
            float4 a; float2 b2;
            a = *(const float4*)&gi_part[t][0];        b2 = *(const float2*)&gi_part[t][4];
            float gir = (a.x + a.y) + (a.z + a.w) + (b2.x + b2.y) + bir;
            a = *(const float4*)&gi_part[128 + t][0];  b2 = *(const float2*)&gi_part[128 + t][4];
            float giz = (a.x + a.y) + (a.z + a.w) + (b2.x + b2.y) + biz;
            a = *(const float4*)&gi_part[256 + t][0];  b2 = *(const float2*)&gi_part[256 + t][4];
            float gin = (a.x + a.y) + (a.z + a.w) + (b2.x + b2.y) + bin_;
            float4 c4, d4;
            c4 = *(const float4*)&gh_part[t][0];       d4 = *(const float4*)&gh_part[t][4];
            float ghr = ((c4.x + c4.y) + (c4.z + c4.w)) + ((d4.x + d4.y) + (d4.z + d4.w)) + bhr;
            c4 = *(const float4*)&gh_part[128 + t][0]; d4 = *(const float4*)&gh_part[128 + t][4];
            float ghz = ((c4.x + c4.y) + (c4.z + c4.w)) + ((d4.x + d4.y) + (d4.z + d4.w)) + bhz;
            c4 = *(const float4*)&gh_part[256 + t][0]; d4 = *(const float4*)&gh_part[256 + t][4];
            float ghn = ((c4.x + c4.y) + (c4.z + c4.w)) + ((d4.x + d4.y) + (d4.z + d4.w)) + bhn;
            float r  = fast_sigmoid(gir + ghr);
            float zg = fast_sigmoid(giz + ghz);
            float nn = fast_tanh(fmaf(r, ghn, gin));
            float hnew = fmaf(zg, hreg - nn, nn);      // (1-z)*n + z*h
            hreg = hnew;
            XH[64 + t] = (_Float16)hnew;
            orow[l * HID + t] = hnew;
        }
        __syncthreads();
    }

    if (t < 128) out[NROWS * LSTEPS * HID + n * HID + t] = hreg;
}

extern "C" void kernel_launch(void* const* d_in, const int* in_sizes, int n_in,
                              void* d_out, int out_size, void* d_ws, size_t ws_size,
                              hipStream_t stream) {
    const float* X   = (const float*)d_in[0];
    const float* EZ  = (const float*)d_in[1];
    const float* EX  = (const float*)d_in[2];
    const float* Wq  = (const float*)d_in[3];
    const float* bq  = (const float*)d_in[4];
    const float* Wp  = (const float*)d_in[5];
    const float* bp  = (const float*)d_in[6];
    const float* Wih = (const float*)d_in[7];
    const float* Whh = (const float*)d_in[8];
    const float* bih = (const float*)d_in[9];
    const float* bhh = (const float*)d_in[10];
    float* out = (float*)d_out;

    vrnn_kernel<<<dim3(NROWS), dim3(1024), 0, stream>>>(
        X, EZ, EX, Wq, bq, Wp, bp, Wih, Whh, bih, bhh, out);
}